// Round 2
// baseline (676.430 us; speedup 1.0000x reference)
//
#include <hip/hip_runtime.h>
#include <hip/hip_bf16.h>

typedef unsigned short u16;
typedef __bf16 bf16x8 __attribute__((ext_vector_type(8)));
typedef u16 u16x8 __attribute__((ext_vector_type(8)));
typedef float f32x4 __attribute__((ext_vector_type(4)));

#define S_LEN 2048
#define NH 8
#define DMODEL 512
#define TOPK 204

__device__ __forceinline__ u16 f2b(float f) {
  __hip_bfloat16 h = __float2bfloat16(f);
  return __builtin_bit_cast(u16, h);
}

// ---------------- transpose fp32 (R x C) -> bf16 (C x R) ----------------
__global__ void transpose_w(const float* __restrict__ in, u16* __restrict__ out, int R, int C) {
  __shared__ float tile[32][33];
  int c0 = blockIdx.x * 32, r0 = blockIdx.y * 32;
  int tx = threadIdx.x & 31, ty = threadIdx.x >> 5;  // 32 x 8
#pragma unroll
  for (int i = 0; i < 32; i += 8)
    tile[ty + i][tx] = in[(long long)(r0 + ty + i) * C + c0 + tx];
  __syncthreads();
#pragma unroll
  for (int i = 0; i < 32; i += 8)
    out[(long long)(c0 + ty + i) * R + r0 + tx] = f2b(tile[tx][ty + i]);
}

// ---------------- fp32 -> bf16 convert ----------------
__global__ void conv_b(const float* __restrict__ in, u16* __restrict__ out, int n) {
  int i = blockIdx.x * 256 + threadIdx.x;
  if (i < n) out[i] = f2b(in[i]);
}

// ---------------- generic bf16 GEMM: C = A(MxK) @ BT(NxK)^T * scale + bias ----------------
// MODE 0: outF fp32 row-major
// MODE 2: outB bf16 at [b][h][s][dk] (Q/K layout), m=b*S+s, n=h*64+dk
// MODE 3: outB bf16 at [b*NH+h][dk][s] (V^T layout)
// MODE 4: outF fp32 + outB bf16 row-major
template <int MODE>
__global__ __launch_bounds__(256) void gemm_bt(
    const u16* __restrict__ A, const u16* __restrict__ BT, const float* __restrict__ bias,
    float* __restrict__ outF, u16* __restrict__ outB,
    int M, int N, int K, float scale) {
  __shared__ u16 As[128 * 32];
  __shared__ u16 Bs[128 * 32];
  int n0 = blockIdx.x * 128, m0 = blockIdx.y * 128;
  int t = threadIdx.x;
  int lane = t & 63, wv = t >> 6;
  int mw = (wv & 1) * 64, nw = (wv >> 1) * 64;
  int fr = lane & 15, fg = lane >> 4;
  f32x4 acc[4][4] = {};
  for (int kt = 0; kt < K; kt += 32) {
    int e0 = t * 8;
    int r0r = e0 >> 5, c0c = e0 & 31;
    int e1 = e0 + 2048;
    int r1r = e1 >> 5, c1c = e1 & 31;
    *(u16x8*)&As[e0] = *(const u16x8*)&A[(long long)(m0 + r0r) * K + kt + c0c];
    *(u16x8*)&As[e1] = *(const u16x8*)&A[(long long)(m0 + r1r) * K + kt + c1c];
    *(u16x8*)&Bs[e0] = *(const u16x8*)&BT[(long long)(n0 + r0r) * K + kt + c0c];
    *(u16x8*)&Bs[e1] = *(const u16x8*)&BT[(long long)(n0 + r1r) * K + kt + c1c];
    __syncthreads();
    bf16x8 af[4], bfv[4];
#pragma unroll
    for (int i = 0; i < 4; i++) af[i] = *(const bf16x8*)&As[(mw + i * 16 + fr) * 32 + fg * 8];
#pragma unroll
    for (int i = 0; i < 4; i++) bfv[i] = *(const bf16x8*)&Bs[(nw + i * 16 + fr) * 32 + fg * 8];
#pragma unroll
    for (int i = 0; i < 4; i++)
#pragma unroll
      for (int j = 0; j < 4; j++)
        acc[i][j] = __builtin_amdgcn_mfma_f32_16x16x32_bf16(af[i], bfv[j], acc[i][j], 0, 0, 0);
    __syncthreads();
  }
#pragma unroll
  for (int i = 0; i < 4; i++)
#pragma unroll
    for (int j = 0; j < 4; j++) {
      int mloc = mw + i * 16 + fg * 4;
      int n = n0 + nw + j * 16 + fr;
      float bvl = bias ? bias[n] : 0.f;
#pragma unroll
      for (int r = 0; r < 4; r++) {
        int m = m0 + mloc + r;
        float v = acc[i][j][r] * scale + bvl;
        if constexpr (MODE == 0) {
          outF[(long long)m * N + n] = v;
        } else if constexpr (MODE == 4) {
          outF[(long long)m * N + n] = v;
          outB[(long long)m * N + n] = f2b(v);
        } else if constexpr (MODE == 2) {
          outB[(long long)((m >> 11) * NH + (n >> 6)) * (S_LEN * 64) + (long long)(m & 2047) * 64 + (n & 63)] = f2b(v);
        } else if constexpr (MODE == 3) {
          outB[((long long)((m >> 11) * NH + (n >> 6)) * 64 + (n & 63)) * S_LEN + (m & 2047)] = f2b(v);
        }
      }
    }
}

// ---------------- Kernel A: per-row (thr, max) via MFMA scores + binary-search top-k ----------------
// grid (128, 16): 16 query rows per block, one (b,h) per blockIdx.y. block = 256.
__global__ __launch_bounds__(256) void score_stats(
    const u16* __restrict__ Qb, const u16* __restrict__ Kb, float2* __restrict__ rowstats) {
  __shared__ u16 Qs[16 * 64];    // 2 KB, chunk-swizzled
  __shared__ u16 Ks[64 * 64];    // 8 KB, chunk-swizzled
  __shared__ u16 Ss[16 * 2048];  // 64 KB mapped keys
  int bh = blockIdx.y;
  int m0 = blockIdx.x * 16;
  int t = threadIdx.x;
  int lane = t & 63, wv = t >> 6;
  int fr = lane & 15, fg = lane >> 4;
  const u16* Qg = Qb + ((long long)bh * S_LEN + m0) * 64;
  const u16* Kg = Kb + (long long)bh * S_LEN * 64;
  if (t < 128) {
    int row = t >> 3, cc = t & 7;
    *(u16x8*)&Qs[row * 64 + ((cc ^ (row & 7)) * 8)] = *(const u16x8*)&Qg[row * 64 + cc * 8];
  }
  __syncthreads();
  bf16x8 aq[2];
#pragma unroll
  for (int ks = 0; ks < 2; ks++)
    aq[ks] = *(const bf16x8*)&Qs[fr * 64 + (((fg + 4 * ks) ^ (fr & 7)) * 8)];
  for (int kt = 0; kt < S_LEN; kt += 64) {
    __syncthreads();  // protect Ks from previous iteration readers
#pragma unroll
    for (int i = 0; i < 2; i++) {
      int e = t * 2 + i;
      int row = e >> 3, cc = e & 7;
      *(u16x8*)&Ks[row * 64 + ((cc ^ (row & 7)) * 8)] = *(const u16x8*)&Kg[(long long)(kt + row) * 64 + cc * 8];
    }
    __syncthreads();
    f32x4 acc = {};
    int krow = wv * 16 + fr;
#pragma unroll
    for (int ks = 0; ks < 2; ks++) {
      bf16x8 bk = *(const bf16x8*)&Ks[krow * 64 + (((fg + 4 * ks) ^ (krow & 7)) * 8)];
      acc = __builtin_amdgcn_mfma_f32_16x16x32_bf16(aq[ks], bk, acc, 0, 0, 0);
    }
#pragma unroll
    for (int r = 0; r < 4; r++) {
      float s = acc[r] * 0.125f;
      u16 b = f2b(s);
      u16 key = (u16)(b ^ ((b & 0x8000) ? 0xFFFFu : 0x8000u));  // monotone map
      Ss[(fg * 4 + r) * 2048 + kt + wv * 16 + fr] = key;
    }
  }
  __syncthreads();
  // per-wave: 4 rows each
  for (int rr = wv * 4; rr < wv * 4 + 4; rr++) {
    const unsigned int* p32 = (const unsigned int*)&Ss[rr * 2048];
    unsigned int kp[16];
#pragma unroll
    for (int j = 0; j < 16; j++) kp[j] = p32[lane + 64 * j];
    unsigned int mx = 0;
#pragma unroll
    for (int j = 0; j < 16; j++) {
      unsigned int a = kp[j] & 0xFFFFu, b = kp[j] >> 16;
      mx = max(mx, max(a, b));
    }
#pragma unroll
    for (int o = 1; o < 64; o <<= 1) mx = max(mx, (unsigned int)__shfl_xor((int)mx, o));
    // largest T with count(key >= T) >= TOPK  ==  TOPK-th largest key
    unsigned int lo = 0, hi = 65535;
    while (lo < hi) {
      unsigned int mid = (lo + hi + 1) >> 1;
      int c = 0;
#pragma unroll
      for (int j = 0; j < 16; j++) {
        c += ((kp[j] & 0xFFFFu) >= mid) ? 1 : 0;
        c += ((kp[j] >> 16) >= mid) ? 1 : 0;
      }
#pragma unroll
      for (int o = 1; o < 64; o <<= 1) c += __shfl_xor(c, o);
      if (c >= TOPK) lo = mid; else hi = mid - 1;
    }
    if (lane == 0) {
      unsigned int tk = lo & 0xFFFFu, mk = mx & 0xFFFFu;
      unsigned int tb = (tk & 0x8000u) ? (tk ^ 0x8000u) : (~tk & 0xFFFFu);
      unsigned int mb = (mk & 0x8000u) ? (mk ^ 0x8000u) : (~mk & 0xFFFFu);
      rowstats[(long long)bh * S_LEN + m0 + rr] =
          make_float2(__uint_as_float(tb << 16), __uint_as_float(mb << 16));
    }
  }
}

// ---------------- Kernel B: flash-style masked-softmax PV with recomputed scores ----------------
// grid (16, 16): 128 rows per block, one (b,h). block = 512 (8 waves x 16 rows).
__global__ __launch_bounds__(512) void attn_pv(
    const u16* __restrict__ Qb, const u16* __restrict__ Kb, const u16* __restrict__ VTb,
    const float2* __restrict__ rowstats, u16* __restrict__ aoB) {
  __shared__ u16 Qs[128 * 64];  // 16 KB swizzled
  __shared__ u16 Ks[32 * 64];   // 4 KB swizzled
  __shared__ u16 Vs[64 * 32];   // 4 KB
  __shared__ u16 Ps[128 * 32];  // 8 KB
  __shared__ float2 st[128];
  int bh = blockIdx.y;
  int m0 = blockIdx.x * 128;
  int t = threadIdx.x;
  int lane = t & 63, wv = t >> 6;
  int fr = lane & 15, fg = lane >> 4;
  int mw = wv * 16;
  const u16* Qg = Qb + ((long long)bh * S_LEN + m0) * 64;
  const u16* Kg = Kb + (long long)bh * S_LEN * 64;
  const u16* Vg = VTb + (long long)bh * 64 * S_LEN;
#pragma unroll
  for (int i = 0; i < 2; i++) {
    int e = t * 2 + i;  // 0..1023
    int row = e >> 3, cc = e & 7;
    *(u16x8*)&Qs[row * 64 + ((cc ^ (row & 7)) * 8)] = *(const u16x8*)&Qg[(long long)row * 64 + cc * 8];
  }
  if (t < 128) st[t] = rowstats[(long long)bh * S_LEN + m0 + t];
  __syncthreads();
  bf16x8 aq[2];
#pragma unroll
  for (int ks = 0; ks < 2; ks++) {
    int row = mw + fr;
    aq[ks] = *(const bf16x8*)&Qs[row * 64 + (((fg + 4 * ks) ^ (row & 7)) * 8)];
  }
  f32x4 acc_o[4] = {};
  float zk[4] = {};
  float2 stv[4];
#pragma unroll
  for (int r = 0; r < 4; r++) stv[r] = st[mw + fg * 4 + r];
  for (int kt = 0; kt < S_LEN; kt += 32) {
    if (t < 256) {
      int row = t >> 3, cc = t & 7;
      *(u16x8*)&Ks[row * 64 + ((cc ^ (row & 7)) * 8)] = *(const u16x8*)&Kg[(long long)(kt + row) * 64 + cc * 8];
    } else {
      int t2 = t - 256;
      int row = t2 >> 2, c = t2 & 3;
      *(u16x8*)&Vs[row * 32 + c * 8] = *(const u16x8*)&Vg[(long long)row * S_LEN + kt + c * 8];
    }
    __syncthreads();
    f32x4 acc_s[2] = {};
#pragma unroll
    for (int ks = 0; ks < 2; ks++)
#pragma unroll
      for (int j = 0; j < 2; j++) {
        int krow = j * 16 + fr;
        bf16x8 bk = *(const bf16x8*)&Ks[krow * 64 + (((fg + 4 * ks) ^ (krow & 7)) * 8)];
        acc_s[j] = __builtin_amdgcn_mfma_f32_16x16x32_bf16(aq[ks], bk, acc_s[j], 0, 0, 0);
      }
#pragma unroll
    for (int j = 0; j < 2; j++)
#pragma unroll
      for (int r = 0; r < 4; r++) {
        float s = acc_s[j][r] * 0.125f;
        float p = (s >= stv[r].x) ? __expf(s - stv[r].y) : 0.f;
        zk[r] += p;
        Ps[(mw + fg * 4 + r) * 32 + j * 16 + fr] = f2b(p);
      }
    bf16x8 pa = *(const bf16x8*)&Ps[(mw + fr) * 32 + fg * 8];
#pragma unroll
    for (int j = 0; j < 4; j++) {
      bf16x8 bv = *(const bf16x8*)&Vs[(j * 16 + fr) * 32 + fg * 8];
      acc_o[j] = __builtin_amdgcn_mfma_f32_16x16x32_bf16(pa, bv, acc_o[j], 0, 0, 0);
    }
    __syncthreads();
  }
#pragma unroll
  for (int r = 0; r < 4; r++) {
#pragma unroll
    for (int o = 1; o < 16; o <<= 1) zk[r] += __shfl_xor(zk[r], o);
    zk[r] = 1.f / zk[r];
  }
  int b = bh >> 3, h = bh & 7;
  long long ob = (long long)b * S_LEN * DMODEL + h * 64;
#pragma unroll
  for (int j = 0; j < 4; j++)
#pragma unroll
    for (int r = 0; r < 4; r++) {
      int row = m0 + mw + fg * 4 + r;
      int dk = j * 16 + fr;
      aoB[ob + (long long)row * DMODEL + dk] = f2b(acc_o[j][r] * zk[r]);
    }
}

// ---------------- residual + LayerNorm (row of 512), writes fp32 + bf16 ----------------
__global__ __launch_bounds__(256) void resid_ln(const float* __restrict__ h, const float* __restrict__ fco,
                                                const float* __restrict__ g, const float* __restrict__ b,
                                                float* __restrict__ hout, u16* __restrict__ hbout) {
  __shared__ float red[4];
  int row = blockIdx.x;
  int t = threadIdx.x;
  long long base = (long long)row * 512;
  float v0 = h[base + t] + fco[base + t];
  float v1 = h[base + t + 256] + fco[base + t + 256];
  float s = v0 + v1;
#pragma unroll
  for (int o = 32; o > 0; o >>= 1) s += __shfl_down(s, o);
  if ((t & 63) == 0) red[t >> 6] = s;
  __syncthreads();
  float mu = (red[0] + red[1] + red[2] + red[3]) * (1.f / 512.f);
  float d0 = v0 - mu, d1 = v1 - mu;
  float q = d0 * d0 + d1 * d1;
#pragma unroll
  for (int o = 32; o > 0; o >>= 1) q += __shfl_down(q, o);
  __syncthreads();
  if ((t & 63) == 0) red[t >> 6] = q;
  __syncthreads();
  float var = (red[0] + red[1] + red[2] + red[3]) * (1.f / 512.f);
  float rs = rsqrtf(var + 1e-5f);
  float y0 = d0 * rs * g[t] + b[t];
  float y1 = d1 * rs * g[t + 256] + b[t + 256];
  hout[base + t] = y0;
  hout[base + t + 256] = y1;
  hbout[base + t] = f2b(y0);
  hbout[base + t + 256] = f2b(y1);
}

// ---------------- decoder ----------------
__global__ void decoder_k(const float* __restrict__ h, const float* __restrict__ W,
                          const float* __restrict__ bias, float* __restrict__ out) {
  int t = threadIdx.x;  // 0..127
  int b = t >> 6, j = t & 63;
  const float* hr = h + ((long long)b * S_LEN + (S_LEN - 1)) * DMODEL;
  float s = 0.f;
  for (int d = 0; d < DMODEL; d++) s += hr[d] * W[(long long)d * 64 + j];
  out[t] = s + bias[j];
}

extern "C" void kernel_launch(void* const* d_in, const int* in_sizes, int n_in,
                              void* d_out, int out_size, void* d_ws, size_t ws_size,
                              hipStream_t stream) {
  const float* x = (const float*)d_in[0];
  const float* enc_W = (const float*)d_in[1];
  const float* enc_b = (const float*)d_in[2];
  const float* Wq = (const float*)d_in[3];
  const float* bq = (const float*)d_in[4];
  const float* Wk = (const float*)d_in[5];
  const float* bk = (const float*)d_in[6];
  const float* Wv = (const float*)d_in[7];
  const float* bv = (const float*)d_in[8];
  const float* fcW = (const float*)d_in[9];
  const float* fcb = (const float*)d_in[10];
  const float* ln_g = (const float*)d_in[11];
  const float* ln_b = (const float*)d_in[12];
  const float* dec_W = (const float*)d_in[13];
  const float* dec_b = (const float*)d_in[14];

  char* p = (char*)d_ws;
  auto alloc = [&](size_t bytes) {
    char* r = p;
    p += (bytes + 255) & ~(size_t)255;
    return r;
  };
  const size_t BS = 2 * (size_t)S_LEN;  // 4096 rows
  u16* encWT = (u16*)alloc(512 * 64 * 2);
  u16* xbf = (u16*)alloc(BS * 64 * 2);
  float* hF = (float*)alloc(BS * 512 * 4);
  u16* hB = (u16*)alloc(BS * 512 * 2);
  u16* WqT = (u16*)alloc(512 * 512 * 2);
  u16* WkT = (u16*)alloc(512 * 512 * 2);
  u16* WvT = (u16*)alloc(512 * 512 * 2);
  u16* fcWT = (u16*)alloc(512 * 512 * 2);
  u16* Qb = (u16*)alloc((size_t)16 * 2048 * 64 * 2);   // 4 MB
  u16* Kb = (u16*)alloc((size_t)16 * 2048 * 64 * 2);   // 4 MB (contiguous after Qb)
  u16* VTb = (u16*)alloc((size_t)16 * 2048 * 64 * 2);  // 4 MB
  float2* rstat = (float2*)alloc((size_t)16 * 2048 * 8);
  u16* aoB = (u16*)alloc(BS * 512 * 2);
  float* fcO = (float*)Qb;  // alias: Qb+Kb (8 MB) dead once attn_pv is done

  transpose_w<<<dim3(16, 2), 256, 0, stream>>>(enc_W, encWT, 64, 512);
  conv_b<<<(int)(BS * 64 / 256), 256, 0, stream>>>(x, xbf, (int)(BS * 64));
  gemm_bt<4><<<dim3(4, 32), 256, 0, stream>>>(xbf, encWT, enc_b, hF, hB, 4096, 512, 64, 1.f);

  for (int l = 0; l < 2; l++) {
    transpose_w<<<dim3(16, 16), 256, 0, stream>>>(Wq + (size_t)l * 512 * 512, WqT, 512, 512);
    transpose_w<<<dim3(16, 16), 256, 0, stream>>>(Wk + (size_t)l * 512 * 512, WkT, 512, 512);
    transpose_w<<<dim3(16, 16), 256, 0, stream>>>(Wv + (size_t)l * 512 * 512, WvT, 512, 512);
    transpose_w<<<dim3(16, 16), 256, 0, stream>>>(fcW + (size_t)l * 512 * 512, fcWT, 512, 512);
    gemm_bt<2><<<dim3(4, 32), 256, 0, stream>>>(hB, WqT, bq + l * 512, nullptr, Qb, 4096, 512, 512, 1.f);
    gemm_bt<2><<<dim3(4, 32), 256, 0, stream>>>(hB, WkT, bk + l * 512, nullptr, Kb, 4096, 512, 512, 1.f);
    gemm_bt<3><<<dim3(4, 32), 256, 0, stream>>>(hB, WvT, bv + l * 512, nullptr, VTb, 4096, 512, 512, 1.f);
    score_stats<<<dim3(128, 16), 256, 0, stream>>>(Qb, Kb, rstat);
    attn_pv<<<dim3(16, 16), 512, 0, stream>>>(Qb, Kb, VTb, rstat, aoB);
    gemm_bt<0><<<dim3(4, 32), 256, 0, stream>>>(aoB, fcWT, fcb + l * 512, fcO, nullptr, 4096, 512, 512, 1.f);
    resid_ln<<<4096, 256, 0, stream>>>(hF, fcO, ln_g + l * 512, ln_b + l * 512, hF, hB);
  }
  decoder_k<<<1, 128, 0, stream>>>(hF, dec_W, dec_b, (float*)d_out);
}

// Round 3
// 591.644 us; speedup vs baseline: 1.1433x; 1.1433x over previous
//
#include <hip/hip_runtime.h>
#include <hip/hip_bf16.h>

typedef unsigned short u16;
typedef __bf16 bf16x8 __attribute__((ext_vector_type(8)));
typedef u16 u16x8 __attribute__((ext_vector_type(8)));
typedef float f32x4 __attribute__((ext_vector_type(4)));

#define S_LEN 2048
#define NH 8
#define DMODEL 512
#define TOPK 204

__device__ __forceinline__ u16 f2b(float f) {
  __hip_bfloat16 h = __float2bfloat16(f);
  return __builtin_bit_cast(u16, h);
}

// ---------------- transpose fp32 (R x C) -> bf16 (C x R) ----------------
__global__ void transpose_w(const float* __restrict__ in, u16* __restrict__ out, int R, int C) {
  __shared__ float tile[32][33];
  int c0 = blockIdx.x * 32, r0 = blockIdx.y * 32;
  int tx = threadIdx.x & 31, ty = threadIdx.x >> 5;  // 32 x 8
#pragma unroll
  for (int i = 0; i < 32; i += 8)
    tile[ty + i][tx] = in[(long long)(r0 + ty + i) * C + c0 + tx];
  __syncthreads();
#pragma unroll
  for (int i = 0; i < 32; i += 8)
    out[(long long)(c0 + ty + i) * R + r0 + tx] = f2b(tile[tx][ty + i]);
}

// ---------------- fp32 -> bf16 convert ----------------
__global__ void conv_b(const float* __restrict__ in, u16* __restrict__ out, int n) {
  int i = blockIdx.x * 256 + threadIdx.x;
  if (i < n) out[i] = f2b(in[i]);
}

// ---------------- generic bf16 GEMM: C = A(MxK) @ BT(NxK)^T * scale + bias ----------------
// MODE 0: outF fp32 row-major
// MODE 2: outB bf16 at [b][h][s][dk] (Q/K layout), m=b*S+s, n=h*64+dk
// MODE 3: outB bf16 at [b*NH+h][dk][s] (V^T layout)
// MODE 4: outF fp32 + outB bf16 row-major
template <int MODE>
__global__ __launch_bounds__(256) void gemm_bt(
    const u16* __restrict__ A, const u16* __restrict__ BT, const float* __restrict__ bias,
    float* __restrict__ outF, u16* __restrict__ outB,
    int M, int N, int K, float scale) {
  __shared__ u16 As[128 * 32];
  __shared__ u16 Bs[128 * 32];
  int n0 = blockIdx.x * 128, m0 = blockIdx.y * 128;
  int t = threadIdx.x;
  int lane = t & 63, wv = t >> 6;
  int mw = (wv & 1) * 64, nw = (wv >> 1) * 64;
  int fr = lane & 15, fg = lane >> 4;
  f32x4 acc[4][4] = {};
  for (int kt = 0; kt < K; kt += 32) {
    int e0 = t * 8;
    int r0r = e0 >> 5, c0c = e0 & 31;
    int e1 = e0 + 2048;
    int r1r = e1 >> 5, c1c = e1 & 31;
    *(u16x8*)&As[e0] = *(const u16x8*)&A[(long long)(m0 + r0r) * K + kt + c0c];
    *(u16x8*)&As[e1] = *(const u16x8*)&A[(long long)(m0 + r1r) * K + kt + c1c];
    *(u16x8*)&Bs[e0] = *(const u16x8*)&BT[(long long)(n0 + r0r) * K + kt + c0c];
    *(u16x8*)&Bs[e1] = *(const u16x8*)&BT[(long long)(n0 + r1r) * K + kt + c1c];
    __syncthreads();
    bf16x8 af[4], bfv[4];
#pragma unroll
    for (int i = 0; i < 4; i++) af[i] = *(const bf16x8*)&As[(mw + i * 16 + fr) * 32 + fg * 8];
#pragma unroll
    for (int i = 0; i < 4; i++) bfv[i] = *(const bf16x8*)&Bs[(nw + i * 16 + fr) * 32 + fg * 8];
#pragma unroll
    for (int i = 0; i < 4; i++)
#pragma unroll
      for (int j = 0; j < 4; j++)
        acc[i][j] = __builtin_amdgcn_mfma_f32_16x16x32_bf16(af[i], bfv[j], acc[i][j], 0, 0, 0);
    __syncthreads();
  }
#pragma unroll
  for (int i = 0; i < 4; i++)
#pragma unroll
    for (int j = 0; j < 4; j++) {
      int mloc = mw + i * 16 + fg * 4;
      int n = n0 + nw + j * 16 + fr;
      float bvl = bias ? bias[n] : 0.f;
#pragma unroll
      for (int r = 0; r < 4; r++) {
        int m = m0 + mloc + r;
        float v = acc[i][j][r] * scale + bvl;
        if constexpr (MODE == 0) {
          outF[(long long)m * N + n] = v;
        } else if constexpr (MODE == 4) {
          outF[(long long)m * N + n] = v;
          outB[(long long)m * N + n] = f2b(v);
        } else if constexpr (MODE == 2) {
          outB[(long long)((m >> 11) * NH + (n >> 6)) * (S_LEN * 64) + (long long)(m & 2047) * 64 + (n & 63)] = f2b(v);
        } else if constexpr (MODE == 3) {
          outB[((long long)((m >> 11) * NH + (n >> 6)) * 64 + (n & 63)) * S_LEN + (m & 2047)] = f2b(v);
        }
      }
    }
}

// ---------------- Kernel A: per-row (thr, max) via 2-pass radix histogram select ----------------
// grid (128, 16): 16 query rows per block, one (b,h) per blockIdx.y. block = 256 (4 waves).
__global__ __launch_bounds__(256) void score_stats(
    const u16* __restrict__ Qb, const u16* __restrict__ Kb, float2* __restrict__ rowstats) {
  __shared__ u16 Qs[16 * 64];              // 2 KB swizzled
  __shared__ u16 Ks[128 * 64];             // 16 KB swizzled
  __shared__ unsigned int hist[16][264];   // 16.5 KB (pad 264 to vary banks per row)
  __shared__ unsigned int maxk[16];
  __shared__ int selB[16];
  __shared__ unsigned int selK[16];
  int bh = blockIdx.y;
  int m0 = blockIdx.x * 16;
  int t = threadIdx.x;
  int lane = t & 63, wv = t >> 6;
  int fr = lane & 15, fg = lane >> 4;
  const u16* Qg = Qb + ((long long)bh * S_LEN + m0) * 64;
  const u16* Kg = Kb + (long long)bh * S_LEN * 64;
  // zero hist + maxk, load Q
  unsigned int* hf = &hist[0][0];
  for (int i = t; i < 16 * 264; i += 256) hf[i] = 0u;
  if (t < 16) maxk[t] = 0u;
  if (t < 128) {
    int row = t >> 3, cc = t & 7;
    *(u16x8*)&Qs[row * 64 + ((cc ^ (row & 7)) * 8)] = *(const u16x8*)&Qg[row * 64 + cc * 8];
  }
  __syncthreads();
  bf16x8 aq[2];
#pragma unroll
  for (int ks = 0; ks < 2; ks++)
    aq[ks] = *(const bf16x8*)&Qs[fr * 64 + (((fg + 4 * ks) ^ (fr & 7)) * 8)];

  // single-lane-hit scan: lane owns bins [4*lane, 4*lane+3]; returns true on hit lane
  auto scan_row = [&](const unsigned int* hr, unsigned int k, int& hitbin, unsigned int& krem) -> bool {
    uint4 hv = *(const uint4*)&hr[lane * 4];
    unsigned int g = hv.x + hv.y + hv.z + hv.w;
    unsigned int suf = g;
#pragma unroll
    for (int o = 1; o < 64; o <<= 1) {
      unsigned int v = (unsigned int)__shfl_down((int)suf, o);
      suf += (lane + o < 64) ? v : 0u;
    }
    unsigned int above = suf - g;              // count of keys in bins >= 4*lane+4
    unsigned int c3 = above + hv.w;
    unsigned int c2 = c3 + hv.z;
    unsigned int c1 = c2 + hv.y;
    unsigned int c0 = c1 + hv.x;
    if (c3 >= k && above < k) { hitbin = lane * 4 + 3; krem = k - above; return true; }
    if (c2 >= k && c3 < k)    { hitbin = lane * 4 + 2; krem = k - c3; return true; }
    if (c1 >= k && c2 < k)    { hitbin = lane * 4 + 1; krem = k - c2; return true; }
    if (c0 >= k && c1 < k)    { hitbin = lane * 4 + 0; krem = k - c1; return true; }
    return false;
  };

  // ---------------- PASS 1: high-byte histogram + max ----------------
  unsigned int mx4[4] = {0u, 0u, 0u, 0u};
  for (int kt = 0; kt < S_LEN; kt += 128) {
    __syncthreads();
#pragma unroll
    for (int i = 0; i < 4; i++) {
      int c = t + 256 * i;
      int row = c >> 3, cc = c & 7;
      *(u16x8*)&Ks[row * 64 + ((cc ^ (row & 7)) * 8)] = *(const u16x8*)&Kg[(long long)(kt + row) * 64 + cc * 8];
    }
    __syncthreads();
#pragma unroll
    for (int g = 0; g < 2; g++) {
      int krow = g * 64 + wv * 16 + fr;
      f32x4 acc = {};
#pragma unroll
      for (int ks = 0; ks < 2; ks++) {
        bf16x8 bk = *(const bf16x8*)&Ks[krow * 64 + (((fg + 4 * ks) ^ (krow & 7)) * 8)];
        acc = __builtin_amdgcn_mfma_f32_16x16x32_bf16(aq[ks], bk, acc, 0, 0, 0);
      }
#pragma unroll
      for (int r = 0; r < 4; r++) {
        float s = acc[r] * 0.125f;
        u16 b = f2b(s);
        unsigned int key = (unsigned int)(u16)(b ^ ((b & 0x8000) ? 0xFFFFu : 0x8000u));
        mx4[r] = max(mx4[r], key);
        atomicAdd(&hist[fg * 4 + r][key >> 8], 1u);
      }
    }
  }
#pragma unroll
  for (int r = 0; r < 4; r++) atomicMax(&maxk[fg * 4 + r], mx4[r]);
  __syncthreads();
  // scan 1: wave wv handles rows wv*4 .. wv*4+3
  for (int rr = 0; rr < 4; rr++) {
    int row = wv * 4 + rr;
    int hb;
    unsigned int kr;
    if (scan_row(&hist[row][0], TOPK, hb, kr)) {
      selB[row] = hb;
      selK[row] = kr;
    }
  }
  __syncthreads();
  // re-zero hist; pick up per-row guard values
  for (int i = t; i < 16 * 264; i += 256) hf[i] = 0u;
  int sb[4];
#pragma unroll
  for (int r = 0; r < 4; r++) sb[r] = selB[fg * 4 + r];
  // ---------------- PASS 2: low-byte histogram within selected bucket ----------------
  for (int kt = 0; kt < S_LEN; kt += 128) {
    __syncthreads();
#pragma unroll
    for (int i = 0; i < 4; i++) {
      int c = t + 256 * i;
      int row = c >> 3, cc = c & 7;
      *(u16x8*)&Ks[row * 64 + ((cc ^ (row & 7)) * 8)] = *(const u16x8*)&Kg[(long long)(kt + row) * 64 + cc * 8];
    }
    __syncthreads();
#pragma unroll
    for (int g = 0; g < 2; g++) {
      int krow = g * 64 + wv * 16 + fr;
      f32x4 acc = {};
#pragma unroll
      for (int ks = 0; ks < 2; ks++) {
        bf16x8 bk = *(const bf16x8*)&Ks[krow * 64 + (((fg + 4 * ks) ^ (krow & 7)) * 8)];
        acc = __builtin_amdgcn_mfma_f32_16x16x32_bf16(aq[ks], bk, acc, 0, 0, 0);
      }
#pragma unroll
      for (int r = 0; r < 4; r++) {
        float s = acc[r] * 0.125f;
        u16 b = f2b(s);
        unsigned int key = (unsigned int)(u16)(b ^ ((b & 0x8000) ? 0xFFFFu : 0x8000u));
        if ((int)(key >> 8) == sb[r]) atomicAdd(&hist[fg * 4 + r][key & 255u], 1u);
      }
    }
  }
  __syncthreads();
  // scan 2 + output
  for (int rr = 0; rr < 4; rr++) {
    int row = wv * 4 + rr;
    int hb;
    unsigned int kr;
    if (scan_row(&hist[row][0], selK[row], hb, kr)) {
      unsigned int tk = ((unsigned int)selB[row] << 8) | (unsigned int)hb;
      unsigned int mk = maxk[row] & 0xFFFFu;
      unsigned int tb = (tk & 0x8000u) ? (tk ^ 0x8000u) : (~tk & 0xFFFFu);
      unsigned int mb = (mk & 0x8000u) ? (mk ^ 0x8000u) : (~mk & 0xFFFFu);
      rowstats[(long long)bh * S_LEN + m0 + row] =
          make_float2(__uint_as_float(tb << 16), __uint_as_float(mb << 16));
    }
  }
}

// ---------------- Kernel B: flash-style masked-softmax PV with recomputed scores ----------------
// grid (16, 16): 128 rows per block, one (b,h). block = 512 (8 waves x 16 rows).
__global__ __launch_bounds__(512) void attn_pv(
    const u16* __restrict__ Qb, const u16* __restrict__ Kb, const u16* __restrict__ VTb,
    const float2* __restrict__ rowstats, u16* __restrict__ aoB) {
  __shared__ u16 Qs[128 * 64];  // 16 KB swizzled
  __shared__ u16 Ks[32 * 64];   // 4 KB swizzled
  __shared__ u16 Vs[64 * 32];   // 4 KB
  __shared__ u16 Ps[128 * 32];  // 8 KB
  __shared__ float2 st[128];
  int bh = blockIdx.y;
  int m0 = blockIdx.x * 128;
  int t = threadIdx.x;
  int lane = t & 63, wv = t >> 6;
  int fr = lane & 15, fg = lane >> 4;
  int mw = wv * 16;
  const u16* Qg = Qb + ((long long)bh * S_LEN + m0) * 64;
  const u16* Kg = Kb + (long long)bh * S_LEN * 64;
  const u16* Vg = VTb + (long long)bh * 64 * S_LEN;
#pragma unroll
  for (int i = 0; i < 2; i++) {
    int e = t * 2 + i;  // 0..1023
    int row = e >> 3, cc = e & 7;
    *(u16x8*)&Qs[row * 64 + ((cc ^ (row & 7)) * 8)] = *(const u16x8*)&Qg[(long long)row * 64 + cc * 8];
  }
  if (t < 128) st[t] = rowstats[(long long)bh * S_LEN + m0 + t];
  __syncthreads();
  bf16x8 aq[2];
#pragma unroll
  for (int ks = 0; ks < 2; ks++) {
    int row = mw + fr;
    aq[ks] = *(const bf16x8*)&Qs[row * 64 + (((fg + 4 * ks) ^ (row & 7)) * 8)];
  }
  f32x4 acc_o[4] = {};
  float zk[4] = {};
  float2 stv[4];
#pragma unroll
  for (int r = 0; r < 4; r++) stv[r] = st[mw + fg * 4 + r];
  for (int kt = 0; kt < S_LEN; kt += 32) {
    if (t < 256) {
      int row = t >> 3, cc = t & 7;
      *(u16x8*)&Ks[row * 64 + ((cc ^ (row & 7)) * 8)] = *(const u16x8*)&Kg[(long long)(kt + row) * 64 + cc * 8];
    } else {
      int t2 = t - 256;
      int row = t2 >> 2, c = t2 & 3;
      *(u16x8*)&Vs[row * 32 + c * 8] = *(const u16x8*)&Vg[(long long)row * S_LEN + kt + c * 8];
    }
    __syncthreads();
    f32x4 acc_s[2] = {};
#pragma unroll
    for (int ks = 0; ks < 2; ks++)
#pragma unroll
      for (int j = 0; j < 2; j++) {
        int krow = j * 16 + fr;
        bf16x8 bk = *(const bf16x8*)&Ks[krow * 64 + (((fg + 4 * ks) ^ (krow & 7)) * 8)];
        acc_s[j] = __builtin_amdgcn_mfma_f32_16x16x32_bf16(aq[ks], bk, acc_s[j], 0, 0, 0);
      }
#pragma unroll
    for (int j = 0; j < 2; j++)
#pragma unroll
      for (int r = 0; r < 4; r++) {
        float s = acc_s[j][r] * 0.125f;
        float p = (s >= stv[r].x) ? __expf(s - stv[r].y) : 0.f;
        zk[r] += p;
        Ps[(mw + fg * 4 + r) * 32 + j * 16 + fr] = f2b(p);
      }
    bf16x8 pa = *(const bf16x8*)&Ps[(mw + fr) * 32 + fg * 8];
#pragma unroll
    for (int j = 0; j < 4; j++) {
      bf16x8 bv = *(const bf16x8*)&Vs[(j * 16 + fr) * 32 + fg * 8];
      acc_o[j] = __builtin_amdgcn_mfma_f32_16x16x32_bf16(pa, bv, acc_o[j], 0, 0, 0);
    }
    __syncthreads();
  }
#pragma unroll
  for (int r = 0; r < 4; r++) {
#pragma unroll
    for (int o = 1; o < 16; o <<= 1) zk[r] += __shfl_xor(zk[r], o);
    zk[r] = 1.f / zk[r];
  }
  int b = bh >> 3, h = bh & 7;
  long long ob = (long long)b * S_LEN * DMODEL + h * 64;
#pragma unroll
  for (int j = 0; j < 4; j++)
#pragma unroll
    for (int r = 0; r < 4; r++) {
      int row = m0 + mw + fg * 4 + r;
      int dk = j * 16 + fr;
      aoB[ob + (long long)row * DMODEL + dk] = f2b(acc_o[j][r] * zk[r]);
    }
}

// ---------------- residual + LayerNorm (row of 512), writes fp32 + bf16 ----------------
__global__ __launch_bounds__(256) void resid_ln(const float* __restrict__ h, const float* __restrict__ fco,
                                                const float* __restrict__ g, const float* __restrict__ b,
                                                float* __restrict__ hout, u16* __restrict__ hbout) {
  __shared__ float red[4];
  int row = blockIdx.x;
  int t = threadIdx.x;
  long long base = (long long)row * 512;
  float v0 = h[base + t] + fco[base + t];
  float v1 = h[base + t + 256] + fco[base + t + 256];
  float s = v0 + v1;
#pragma unroll
  for (int o = 32; o > 0; o >>= 1) s += __shfl_down(s, o);
  if ((t & 63) == 0) red[t >> 6] = s;
  __syncthreads();
  float mu = (red[0] + red[1] + red[2] + red[3]) * (1.f / 512.f);
  float d0 = v0 - mu, d1 = v1 - mu;
  float q = d0 * d0 + d1 * d1;
#pragma unroll
  for (int o = 32; o > 0; o >>= 1) q += __shfl_down(q, o);
  __syncthreads();
  if ((t & 63) == 0) red[t >> 6] = q;
  __syncthreads();
  float var = (red[0] + red[1] + red[2] + red[3]) * (1.f / 512.f);
  float rs = rsqrtf(var + 1e-5f);
  float y0 = d0 * rs * g[t] + b[t];
  float y1 = d1 * rs * g[t + 256] + b[t + 256];
  hout[base + t] = y0;
  hout[base + t + 256] = y1;
  hbout[base + t] = f2b(y0);
  hbout[base + t + 256] = f2b(y1);
}

// ---------------- decoder ----------------
__global__ void decoder_k(const float* __restrict__ h, const float* __restrict__ W,
                          const float* __restrict__ bias, float* __restrict__ out) {
  int t = threadIdx.x;  // 0..127
  int b = t >> 6, j = t & 63;
  const float* hr = h + ((long long)b * S_LEN + (S_LEN - 1)) * DMODEL;
  float s = 0.f;
  for (int d = 0; d < DMODEL; d++) s += hr[d] * W[(long long)d * 64 + j];
  out[t] = s + bias[j];
}

extern "C" void kernel_launch(void* const* d_in, const int* in_sizes, int n_in,
                              void* d_out, int out_size, void* d_ws, size_t ws_size,
                              hipStream_t stream) {
  const float* x = (const float*)d_in[0];
  const float* enc_W = (const float*)d_in[1];
  const float* enc_b = (const float*)d_in[2];
  const float* Wq = (const float*)d_in[3];
  const float* bq = (const float*)d_in[4];
  const float* Wk = (const float*)d_in[5];
  const float* bk = (const float*)d_in[6];
  const float* Wv = (const float*)d_in[7];
  const float* bv = (const float*)d_in[8];
  const float* fcW = (const float*)d_in[9];
  const float* fcb = (const float*)d_in[10];
  const float* ln_g = (const float*)d_in[11];
  const float* ln_b = (const float*)d_in[12];
  const float* dec_W = (const float*)d_in[13];
  const float* dec_b = (const float*)d_in[14];

  char* p = (char*)d_ws;
  auto alloc = [&](size_t bytes) {
    char* r = p;
    p += (bytes + 255) & ~(size_t)255;
    return r;
  };
  const size_t BS = 2 * (size_t)S_LEN;  // 4096 rows
  u16* encWT = (u16*)alloc(512 * 64 * 2);
  u16* xbf = (u16*)alloc(BS * 64 * 2);
  float* hF = (float*)alloc(BS * 512 * 4);
  u16* hB = (u16*)alloc(BS * 512 * 2);
  u16* WqT = (u16*)alloc(512 * 512 * 2);
  u16* WkT = (u16*)alloc(512 * 512 * 2);
  u16* WvT = (u16*)alloc(512 * 512 * 2);
  u16* fcWT = (u16*)alloc(512 * 512 * 2);
  u16* Qb = (u16*)alloc((size_t)16 * 2048 * 64 * 2);   // 4 MB
  u16* Kb = (u16*)alloc((size_t)16 * 2048 * 64 * 2);   // 4 MB
  u16* VTb = (u16*)alloc((size_t)16 * 2048 * 64 * 2);  // 4 MB
  float2* rstat = (float2*)alloc((size_t)16 * 2048 * 8);
  u16* aoB = (u16*)alloc(BS * 512 * 2);
  float* fcO = (float*)Qb;  // alias: Qb+Kb (8 MB) dead once attn_pv is done

  transpose_w<<<dim3(16, 2), 256, 0, stream>>>(enc_W, encWT, 64, 512);
  conv_b<<<(int)(BS * 64 / 256), 256, 0, stream>>>(x, xbf, (int)(BS * 64));
  gemm_bt<4><<<dim3(4, 32), 256, 0, stream>>>(xbf, encWT, enc_b, hF, hB, 4096, 512, 64, 1.f);

  for (int l = 0; l < 2; l++) {
    transpose_w<<<dim3(16, 16), 256, 0, stream>>>(Wq + (size_t)l * 512 * 512, WqT, 512, 512);
    transpose_w<<<dim3(16, 16), 256, 0, stream>>>(Wk + (size_t)l * 512 * 512, WkT, 512, 512);
    transpose_w<<<dim3(16, 16), 256, 0, stream>>>(Wv + (size_t)l * 512 * 512, WvT, 512, 512);
    transpose_w<<<dim3(16, 16), 256, 0, stream>>>(fcW + (size_t)l * 512 * 512, fcWT, 512, 512);
    gemm_bt<2><<<dim3(4, 32), 256, 0, stream>>>(hB, WqT, bq + l * 512, nullptr, Qb, 4096, 512, 512, 1.f);
    gemm_bt<2><<<dim3(4, 32), 256, 0, stream>>>(hB, WkT, bk + l * 512, nullptr, Kb, 4096, 512, 512, 1.f);
    gemm_bt<3><<<dim3(4, 32), 256, 0, stream>>>(hB, WvT, bv + l * 512, nullptr, VTb, 4096, 512, 512, 1.f);
    score_stats<<<dim3(128, 16), 256, 0, stream>>>(Qb, Kb, rstat);
    attn_pv<<<dim3(16, 16), 512, 0, stream>>>(Qb, Kb, VTb, rstat, aoB);
    gemm_bt<0><<<dim3(4, 32), 256, 0, stream>>>(aoB, fcWT, fcb + l * 512, fcO, nullptr, 4096, 512, 512, 1.f);
    resid_ln<<<4096, 256, 0, stream>>>(hF, fcO, ln_g + l * 512, ln_b + l * 512, hF, hB);
  }
  decoder_k<<<1, 128, 0, stream>>>(hF, dec_W, dec_b, (float*)d_out);
}